// Round 1
// baseline (75.317 us; speedup 1.0000x reference)
//
#include <hip/hip_runtime.h>
#include <hip/hip_bf16.h>

#define DIM 8192

typedef __bf16 bf16x8 __attribute__((ext_vector_type(8)));
typedef float f32x16 __attribute__((ext_vector_type(16)));

__device__ __forceinline__ unsigned short f2bf(float f) {
  union { float f; unsigned u; } v; v.f = f;
  unsigned r = v.u + 0x7FFFu + ((v.u >> 16) & 1u);   // RNE
  return (unsigned short)(r >> 16);
}

// grid: 512 = 32 m-chunks (x-axis low 5 bits) x 16 k-chunks; block 256 (4 waves)
// wg computes out cols [mc*256, mc*256+256) over k in [kc*512, kc*512+512), atomically added.
__global__ __launch_bounds__(256, 2)
void bcl_mfma_kernel(const float* __restrict__ X,
                     const float* __restrict__ Blk,
                     float* __restrict__ Out) {
  // A: [koct][row][8] bf16, fragment-ordered so a-frag load is a contiguous 1KB ds_read_b128 per wave
  __shared__ __align__(16) unsigned short A_lds[64 * 32 * 8];    // 32 KB
  // B: circulant window, [w][p][24] bf16 (16 used + 8 pad -> 48B p-stride kills 8-word bank period)
  __shared__ __align__(16) unsigned short B_lds[47 * 16 * 24];   // 35.25 KB

  const int tid = threadIdx.x;
  const int mc  = blockIdx.x & 31;   // m-blocks [mc*16, mc*16+16)
  const int kc  = blockIdx.x >> 5;   // n-blocks [kc*32, kc*32+32)
  const int kbase = kc * 512;

  // ---- stage A (x fp32 -> bf16), LDS-linear mapping: conflict-free stores,
  // each wg-iteration covers whole 128B lines of every row (no overfetch)
  #pragma unroll
  for (int it = 0; it < 16; ++it) {
    const int i = tid + it * 256;
    const int L = i << 2;                 // linear bf16 index in A_lds
    const int oct = L >> 8;
    const int r   = (L >> 3) & 31;
    const int j   = L & 7;                // 0 or 4
    const float4 v = *reinterpret_cast<const float4*>(X + r * DIM + kbase + oct * 8 + j);
    ushort4 s;
    s.x = f2bf(v.x); s.y = f2bf(v.y); s.z = f2bf(v.z); s.w = f2bf(v.w);
    *reinterpret_cast<ushort4*>(&A_lds[L]) = s;
  }

  // ---- stage B window: 47 blocks, d = (dbase + w) & 511
  const int dbase = (mc * 16 - kc * 32 - 31 + 512) & 511;
  for (int i = tid; i < 47 * 64; i += 256) {
    const int w = i >> 6;
    const int e = (i & 63) << 2;          // elem in block: p = e>>4, q = e&15
    const int d = (dbase + w) & 511;
    const float4 v = *reinterpret_cast<const float4*>(Blk + d * 256 + e);
    ushort4 s;
    s.x = f2bf(v.x); s.y = f2bf(v.y); s.z = f2bf(v.z); s.w = f2bf(v.w);
    *reinterpret_cast<ushort4*>(&B_lds[w * 384 + (e >> 4) * 24 + (e & 15)]) = s;
  }

  __syncthreads();   // the only barrier; hot loop is pure ds_read + MFMA

  const int lane = tid & 63;
  const int wid  = tid >> 6;
  const int h    = lane >> 5;            // k-half of the MFMA operands
  const int r31  = lane & 31;            // A row (batch) / C col
  const int p    = lane & 15;
  const int msub = (lane >> 4) & 1;      // which m-block within the 32-col tile

  const unsigned short* Ab = &A_lds[(h * 32 + r31) * 8];
  const unsigned short* Bb = &B_lds[p * 24 + h * 8];
  // window index at step s: w = 2*tile + msub + 31 - s  (tile = wid*2 + t)
  const int wt0 = (wid * 2 + 0) * 2 + msub + 31;
  const int wt1 = wt0 + 2;

  f32x16 acc0, acc1;
  #pragma unroll
  for (int i = 0; i < 16; ++i) { acc0[i] = 0.0f; acc1[i] = 0.0f; }

  #pragma unroll 4
  for (int s = 0; s < 32; ++s) {
    const bf16x8 a  = *reinterpret_cast<const bf16x8*>(Ab + s * 512);
    const bf16x8 b0 = *reinterpret_cast<const bf16x8*>(Bb + (wt0 - s) * 384);
    const bf16x8 b1 = *reinterpret_cast<const bf16x8*>(Bb + (wt1 - s) * 384);
    acc0 = __builtin_amdgcn_mfma_f32_32x32x16_bf16(a, b0, acc0, 0, 0, 0);
    acc1 = __builtin_amdgcn_mfma_f32_32x32x16_bf16(a, b1, acc1, 0, 0, 0);
  }

  // ---- epilogue: measured C/D layout col=lane&31, row=(reg&3)+8*(reg>>2)+4*(lane>>5)
  const int colbase = mc * 256 + wid * 64 + r31;
  float* o0 = Out + colbase;
  #pragma unroll
  for (int reg = 0; reg < 16; ++reg) {
    const int row = (reg & 3) + 8 * (reg >> 2) + 4 * h;
    unsafeAtomicAdd(o0 + row * DIM,      acc0[reg]);
    unsafeAtomicAdd(o0 + row * DIM + 32, acc1[reg]);
  }
}

extern "C" void kernel_launch(void* const* d_in, const int* in_sizes, int n_in,
                              void* d_out, int out_size, void* d_ws, size_t ws_size,
                              hipStream_t stream) {
  const float* X   = (const float*)d_in[0];   // [32, 8192] fp32
  const float* Blk = (const float*)d_in[1];   // [512, 16, 16] fp32
  float* Out = (float*)d_out;                 // [32, 8192] fp32
  hipMemsetAsync(Out, 0, (size_t)32 * DIM * sizeof(float), stream);
  bcl_mfma_kernel<<<dim3(512), dim3(256), 0, stream>>>(X, Blk, Out);
}

// Round 2
// 73.413 us; speedup vs baseline: 1.0259x; 1.0259x over previous
//
#include <hip/hip_runtime.h>
#include <hip/hip_bf16.h>

#define DIM 8192
#define KSPLIT 16
#define PARTIAL_ELEMS (32 * DIM)   // one fp32 copy of the output per k-chunk

typedef __bf16 bf16x8 __attribute__((ext_vector_type(8)));
typedef float f32x16 __attribute__((ext_vector_type(16)));

__device__ __forceinline__ unsigned short f2bf(float f) {
  union { float f; unsigned u; } v; v.f = f;
  unsigned r = v.u + 0x7FFFu + ((v.u >> 16) & 1u);   // RNE
  return (unsigned short)(r >> 16);
}

// grid: 512 = 32 m-chunks (low 5 bits) x 16 k-chunks; block 256 (4 waves)
// wg computes partial out cols [mc*256, mc*256+256) over k in [kc*512, kc*512+512),
// plain-stored to Ws[kc][32][8192] (disjoint -> no atomics).
__global__ __launch_bounds__(256, 2)
void bcl_mfma_kernel(const float* __restrict__ X,
                     const float* __restrict__ Blk,
                     float* __restrict__ Ws) {
  // A: [koct][row][8] bf16, fragment-ordered so a-frag load is a contiguous ds_read_b128
  __shared__ __align__(16) unsigned short A_lds[64 * 32 * 8];    // 32 KB
  // B: circulant window, [w][p][24] bf16 (16 used + 8 pad -> 48B p-stride)
  __shared__ __align__(16) unsigned short B_lds[47 * 16 * 24];   // 35.25 KB

  const int tid = threadIdx.x;
  const int mc  = blockIdx.x & 31;   // m-blocks [mc*16, mc*16+16)
  const int kc  = blockIdx.x >> 5;   // n-blocks [kc*32, kc*32+32)
  const int kbase = kc * 512;

  // ---- stage A (x fp32 -> bf16), conflict-free linear stores
  #pragma unroll
  for (int it = 0; it < 16; ++it) {
    const int i = tid + it * 256;
    const int L = i << 2;                 // linear bf16 index in A_lds
    const int oct = L >> 8;
    const int r   = (L >> 3) & 31;
    const int j   = L & 7;                // 0 or 4
    const float4 v = *reinterpret_cast<const float4*>(X + r * DIM + kbase + oct * 8 + j);
    ushort4 s;
    s.x = f2bf(v.x); s.y = f2bf(v.y); s.z = f2bf(v.z); s.w = f2bf(v.w);
    *reinterpret_cast<ushort4*>(&A_lds[L]) = s;
  }

  // ---- stage B window: 47 blocks, d = (dbase + w) & 511
  const int dbase = (mc * 16 - kc * 32 - 31 + 512) & 511;
  for (int i = tid; i < 47 * 64; i += 256) {
    const int w = i >> 6;
    const int e = (i & 63) << 2;          // elem in block: p = e>>4, q = e&15
    const int d = (dbase + w) & 511;
    const float4 v = *reinterpret_cast<const float4*>(Blk + d * 256 + e);
    ushort4 s;
    s.x = f2bf(v.x); s.y = f2bf(v.y); s.z = f2bf(v.z); s.w = f2bf(v.w);
    *reinterpret_cast<ushort4*>(&B_lds[w * 384 + (e >> 4) * 24 + (e & 15)]) = s;
  }

  __syncthreads();   // the only barrier; hot loop is pure ds_read + MFMA

  const int lane = tid & 63;
  const int wid  = tid >> 6;
  const int h    = lane >> 5;            // k-half of the MFMA operands
  const int r31  = lane & 31;            // A row (batch) / C col
  const int p    = lane & 15;
  const int msub = (lane >> 4) & 1;      // which m-block within the 32-col tile

  const unsigned short* Ab = &A_lds[(h * 32 + r31) * 8];
  const unsigned short* Bb = &B_lds[p * 24 + h * 8];
  const int wt0 = (wid * 2 + 0) * 2 + msub + 31;
  const int wt1 = wt0 + 2;

  f32x16 acc0, acc1;
  #pragma unroll
  for (int i = 0; i < 16; ++i) { acc0[i] = 0.0f; acc1[i] = 0.0f; }

  #pragma unroll 4
  for (int s = 0; s < 32; ++s) {
    const bf16x8 a  = *reinterpret_cast<const bf16x8*>(Ab + s * 512);
    const bf16x8 b0 = *reinterpret_cast<const bf16x8*>(Bb + (wt0 - s) * 384);
    const bf16x8 b1 = *reinterpret_cast<const bf16x8*>(Bb + (wt1 - s) * 384);
    acc0 = __builtin_amdgcn_mfma_f32_32x32x16_bf16(a, b0, acc0, 0, 0, 0);
    acc1 = __builtin_amdgcn_mfma_f32_32x32x16_bf16(a, b1, acc1, 0, 0, 0);
  }

  // ---- epilogue: plain coalesced stores to the wg's private partial tile.
  // C/D layout: col=lane&31, row=(reg&3)+8*(reg>>2)+4*(lane>>5)
  float* o0 = Ws + (size_t)kc * PARTIAL_ELEMS + mc * 256 + wid * 64 + r31;
  #pragma unroll
  for (int reg = 0; reg < 16; ++reg) {
    const int row = (reg & 3) + 8 * (reg >> 2) + 4 * h;
    o0[row * DIM]      = acc0[reg];
    o0[row * DIM + 32] = acc1[reg];
  }
}

// Phase 2: Out = sum over KSPLIT partial copies. 256 wgs x 256 thr, float4 each.
__global__ __launch_bounds__(256)
void bcl_reduce_kernel(const float4* __restrict__ Ws, float4* __restrict__ Out) {
  const int f = blockIdx.x * 256 + threadIdx.x;
  float4 a = Ws[f];
  #pragma unroll
  for (int kc = 1; kc < KSPLIT; ++kc) {
    const float4 v = Ws[kc * (PARTIAL_ELEMS / 4) + f];
    a.x += v.x; a.y += v.y; a.z += v.z; a.w += v.w;
  }
  Out[f] = a;
}

extern "C" void kernel_launch(void* const* d_in, const int* in_sizes, int n_in,
                              void* d_out, int out_size, void* d_ws, size_t ws_size,
                              hipStream_t stream) {
  const float* X   = (const float*)d_in[0];   // [32, 8192] fp32
  const float* Blk = (const float*)d_in[1];   // [512, 16, 16] fp32
  float* Ws  = (float*)d_ws;                  // KSPLIT x 1 MB partials (16 MB)
  float* Out = (float*)d_out;                 // [32, 8192] fp32
  bcl_mfma_kernel<<<dim3(512), dim3(256), 0, stream>>>(X, Blk, Ws);
  bcl_reduce_kernel<<<dim3(PARTIAL_ELEMS / 4 / 256), dim3(256), 0, stream>>>(
      (const float4*)Ws, (float4*)Out);
}

// Round 3
// 73.374 us; speedup vs baseline: 1.0265x; 1.0005x over previous
//
#include <hip/hip_runtime.h>
#include <hip/hip_bf16.h>

#define DIM 8192
#define KSPLIT 16
#define PARTIAL_ELEMS (32 * DIM)   // one fp32 copy of the output per k-chunk

typedef __bf16 bf16x8 __attribute__((ext_vector_type(8)));
typedef float f32x4 __attribute__((ext_vector_type(4)));

__device__ __forceinline__ unsigned short f2bf(float f) {
  union { float f; unsigned u; } v; v.f = f;
  unsigned r = v.u + 0x7FFFu + ((v.u >> 16) & 1u);   // RNE
  return (unsigned short)(r >> 16);
}

// grid: 512 = 32 mc (low 5 bits) x 16 kc; block 256 (4 waves).
// wg: partial out cols [mc*256,+256) over k [kc*512,+512) -> Ws[kc][32][8192].
// Hot loop: 16x16x32 MFMA, BOTH operand reads are wave-contiguous 1KB ds_read_b128
// (conflict-free). Circulant trick: the two k-halves of one MFMA use adjacent
// window slots, so the blocks-fragment is the contiguous 1KB at slots [w0-1, w0+1).
__global__ __launch_bounds__(256, 2)
void bcl_mfma_kernel(const float* __restrict__ X,
                     const float* __restrict__ Blk,
                     float* __restrict__ Ws) {
  // x: [s:16][b0:2][kh:4][p:16][j:8] bf16 (32 KB): frag = contiguous 1KB
  __shared__ __align__(16) unsigned short Xl[16384];
  // blocks window: 47 slots x 512B, each repacked [qh:2][p:16][j:8]
  __shared__ __align__(16) unsigned short Wl[47 * 256];

  const int tid = threadIdx.x;
  const int mc  = blockIdx.x & 31;
  const int kc  = blockIdx.x >> 5;
  const int kbase = kc * 512;

  // ---- stage x (fp32->bf16). LDS stores linear (conflict-free).
  #pragma unroll
  for (int it = 0; it < 16; ++it) {
    const int L  = (tid + it * 256) << 2;     // elem index in Xl
    const int j4 = L & 7;
    const int p  = (L >> 3) & 15;
    const int kh = (L >> 7) & 3;
    const int b0 = (L >> 9) & 1;
    const int s  = (L >> 10) & 15;
    const int batch = b0 * 16 + p;
    const int kg = kbase + s * 32 + (kh >> 1) * 16 + (kh & 1) * 8 + j4;
    const float4 v = *reinterpret_cast<const float4*>(X + batch * DIM + kg);
    ushort4 u;
    u.x = f2bf(v.x); u.y = f2bf(v.y); u.z = f2bf(v.z); u.w = f2bf(v.w);
    *reinterpret_cast<ushort4*>(&Xl[L]) = u;
  }

  // ---- stage blocks window: slot w holds blocks[(dbase+w)&511] as [qh][p][j]
  const int dbase = (mc * 16 - kc * 32 - 31) & 511;
  for (int i = tid; i < 47 * 64; i += 256) {
    const int w  = i >> 6;
    const int r  = (i & 63) << 2;             // elem in repacked block
    const int qh = r >> 7;
    const int p  = (r >> 3) & 15;
    const int j4 = r & 7;
    const int d  = (dbase + w) & 511;
    const float4 v = *reinterpret_cast<const float4*>(Blk + d * 256 + p * 16 + qh * 8 + j4);
    ushort4 u;
    u.x = f2bf(v.x); u.y = f2bf(v.y); u.z = f2bf(v.z); u.w = f2bf(v.w);
    *reinterpret_cast<ushort4*>(&Wl[w * 256 + r]) = u;
  }

  __syncthreads();   // only barrier

  const int lane = tid & 63;
  const int wid  = tid >> 6;

  // x-frag (a-operand): lane l -> Xl[s*1024 + b0*512 + l*8]
  const unsigned short* Xb = &Xl[lane << 3];
  // blocks-frag (b-operand): lanes 0-31 read slot w0, 32-63 read slot w0-1,
  // each half contiguous 512B; flat = (w0-1)*256 elems + per-lane offset:
  const unsigned short* Wb = &Wl[(((lane >> 5) ^ 1) << 8) + (((lane >> 4) & 1) << 7) + ((lane & 15) << 3)];

  f32x4 acc[4][2];
  #pragma unroll
  for (int t = 0; t < 4; ++t)
    #pragma unroll
    for (int b = 0; b < 2; ++b)
      acc[t][b] = (f32x4){0.f, 0.f, 0.f, 0.f};

  #pragma unroll 4
  for (int s = 0; s < 16; ++s) {
    const bf16x8 x0 = *reinterpret_cast<const bf16x8*>(Xb + (s << 10));
    const bf16x8 x1 = *reinterpret_cast<const bf16x8*>(Xb + (s << 10) + 512);
    #pragma unroll
    for (int t = 0; t < 4; ++t) {
      const int mt = (wid << 2) + t;
      const bf16x8 wf = *reinterpret_cast<const bf16x8*>(Wb + ((mt + 30 - 2 * s) << 8));
      acc[t][0] = __builtin_amdgcn_mfma_f32_16x16x32_bf16(x0, wf, acc[t][0], 0, 0, 0);
      acc[t][1] = __builtin_amdgcn_mfma_f32_16x16x32_bf16(x1, wf, acc[t][1], 0, 0, 0);
    }
  }

  // ---- epilogue: C/D 16x16 layout col=lane&15 (=p), row=(lane>>4)*4+reg (=batch-in-half)
  // each store inst: 4 rows x 16 contiguous cols (64B segments)
  float* base = Ws + (size_t)kc * PARTIAL_ELEMS + mc * 256;
  #pragma unroll
  for (int t = 0; t < 4; ++t) {
    const int col = ((wid << 2) + t) * 16 + (lane & 15);
    #pragma unroll
    for (int b0 = 0; b0 < 2; ++b0) {
      const int brow = b0 * 16 + ((lane >> 4) << 2);
      #pragma unroll
      for (int r = 0; r < 4; ++r)
        base[(brow + r) * DIM + col] = acc[t][b0][r];
    }
  }
}

// Phase 2: Out = sum of KSPLIT partials. 256 wgs x 256 thr, float4 each.
__global__ __launch_bounds__(256)
void bcl_reduce_kernel(const float4* __restrict__ Ws, float4* __restrict__ Out) {
  const int f = blockIdx.x * 256 + threadIdx.x;
  float4 a = Ws[f];
  #pragma unroll
  for (int kc = 1; kc < KSPLIT; ++kc) {
    const float4 v = Ws[kc * (PARTIAL_ELEMS / 4) + f];
    a.x += v.x; a.y += v.y; a.z += v.z; a.w += v.w;
  }
  Out[f] = a;
}

extern "C" void kernel_launch(void* const* d_in, const int* in_sizes, int n_in,
                              void* d_out, int out_size, void* d_ws, size_t ws_size,
                              hipStream_t stream) {
  const float* X   = (const float*)d_in[0];   // [32, 8192] fp32
  const float* Blk = (const float*)d_in[1];   // [512, 16, 16] fp32
  float* Ws  = (float*)d_ws;                  // 16 MB partials
  float* Out = (float*)d_out;                 // [32, 8192] fp32
  bcl_mfma_kernel<<<dim3(512), dim3(256), 0, stream>>>(X, Blk, Ws);
  bcl_reduce_kernel<<<dim3(PARTIAL_ELEMS / 4 / 256), dim3(256), 0, stream>>>(
      (const float4*)Ws, (float4*)Out);
}